// Round 1
// baseline (276.556 us; speedup 1.0000x reference)
//
#include <hip/hip_runtime.h>
#include <math.h>

typedef unsigned short u16;
typedef unsigned int   u32;

#define B_       64
#define NN_      64
#define HL_      50
#define IN_DIM   384
#define POS_DIM  64
#define ATT_DIM  256
#define NEWS_DIM 448   // IN_DIM + POS_DIM

typedef __attribute__((ext_vector_type(8))) short short8;   // bf16x8 MFMA frag
typedef __attribute__((ext_vector_type(4))) float f32x4;    // MFMA acc

#if __has_builtin(__builtin_amdgcn_exp2f)
#define EXP2F(x) __builtin_amdgcn_exp2f(x)
#else
#define EXP2F(x) exp2f(x)
#endif
#if __has_builtin(__builtin_amdgcn_rcpf)
#define RCPF(x) __builtin_amdgcn_rcpf(x)
#else
#define RCPF(x) (1.0f/(x))
#endif

__device__ __forceinline__ u16 f2bf(float f) {
    union { float f; u32 i; } v; v.f = f;
    u32 r = v.i + 0x7fffu + ((v.i >> 16) & 1u);   // RNE
    return (u16)(r >> 16);
}
__device__ __forceinline__ float bf2f(u16 u) {
    union { u32 i; float f; } v; v.i = ((u32)u) << 16; return v.f;
}
__device__ __forceinline__ uint2 pack4(float4 v) {
    return make_uint2((u32)f2bf(v.x) | ((u32)f2bf(v.y) << 16),
                      (u32)f2bf(v.z) | ((u32)f2bf(v.w) << 16));
}
// tanh(x) = 1 - 2/(1+2^(x*2*log2e)); v_exp+v_rcp saturate correctly at +-inf.
__device__ __forceinline__ float fast_tanh(float x) {
    float e = EXP2F(x * 2.88539008f);
    return 1.0f - 2.0f * RCPF(1.0f + e);
}

// prep segments, in 4-f32 chunks
#define C_W   57344u     // W1 (256x896) -> Wbf
#define C_NV  393216u    // newsv (4096x384) -> nv_bf AND nf f32 head
#define C_LG  307200u    // logv (3200x384) -> lf_bf head
#define C_PS  51200u     // pos rows 1..50 -> lf_bf tail
#define C_NZ  65536u     // nf f32 zero tail (4096x64)
#define C_TOT (C_W + C_NV + C_LG + C_PS + C_NZ)   // 874,496 = 3416*256

// ---------------- K0: bf16-convert W1/newsv/lf into ws; nf (f32) -> d_out.
__global__ __launch_bounds__(256) void prep_k(
    const float* __restrict__ W1, const float* __restrict__ newsv,
    const float* __restrict__ logv, const float* __restrict__ pos,
    u16* __restrict__ Wbf, u16* __restrict__ nv_bf, u16* __restrict__ lf_bf,
    float* __restrict__ nf)
{
    u32 i = blockIdx.x * 256u + threadIdx.x;
    if (i < C_W) {                                   // W1 -> Wbf
        float4 v = *(const float4*)(W1 + (size_t)i * 4u);
        *(uint2*)(Wbf + (size_t)i * 4u) = pack4(v);
        return;
    }
    i -= C_W;
    if (i < C_NV) {                                  // newsv -> nv_bf + nf head
        float4 v = *(const float4*)(newsv + (size_t)i * 4u);
        *(uint2*)(nv_bf + (size_t)i * 4u) = pack4(v);
        u32 e = i * 4u, r = e / IN_DIM, d = e - r * IN_DIM;
        *(float4*)(nf + (size_t)r * NEWS_DIM + d) = v;
        return;
    }
    i -= C_NV;
    if (i < C_LG) {                                  // logv -> lf_bf head
        float4 v = *(const float4*)(logv + (size_t)i * 4u);
        u32 e = i * 4u, r = e / IN_DIM, d = e - r * IN_DIM;
        *(uint2*)(lf_bf + (size_t)r * NEWS_DIM + d) = pack4(v);
        return;
    }
    i -= C_LG;
    if (i < C_PS) {                                  // pos rows 1..50 -> lf_bf tail
        u32 e = i * 4u, r = e / POS_DIM, d = e - r * POS_DIM;
        u32 h = r % HL_;
        float4 v = *(const float4*)(pos + (size_t)(1u + h) * POS_DIM + d);
        *(uint2*)(lf_bf + (size_t)r * NEWS_DIM + IN_DIM + d) = pack4(v);
        return;
    }
    i -= C_PS;
    if (i < C_NZ) {                                  // nf zero tail
        u32 e = i * 4u, r = e / POS_DIM, d = e - r * POS_DIM;
        *(float4*)(nf + (size_t)r * NEWS_DIM + IN_DIM + d) = make_float4(0.f, 0.f, 0.f, 0.f);
    }
}

// ---------------- K1: fused NT GEMMs, pure bf16 16B loads.
// R11: per-wave tile shrunk 64x64 -> 16x64 (acc 1x4): 456 -> 1824 waves.
// Total FLOPs are trivial (1.5 GF); the kernel is latency-bound, so wave
// count (TLP) is the lever. W re-read traffic rises to ~96MB, all L2 (<3us).
// bid < 1024: pn[4096x256] = nv_bf . Wbf[:, :384]^T + b1
// bid >= 1024: plT[(b*256+a)*50+h] = lf_bf . Wbf[:, 448:]^T (transposed store)
__global__ __launch_bounds__(64) void gemm_k(
    const u16* __restrict__ nv_bf, const u16* __restrict__ lf_bf,
    const u16* __restrict__ Wbf, const float* __restrict__ b1,
    float* __restrict__ pn, float* __restrict__ plT)
{
    int bid = blockIdx.x;
    int lane = threadIdx.x;
    int m = lane & 15, q = lane >> 4;
    bool is_pn = bid < 1024;
    int r0, c0, lda, koff, klen;
    const u16* A;
    if (is_pn) { r0 = (bid >> 2) * 16;  c0 = (bid & 3) * 64; A = nv_bf; lda = IN_DIM;   koff = 0;        klen = IN_DIM; }
    else { int b2 = bid - 1024; r0 = (b2 >> 2) * 16; c0 = (b2 & 3) * 64; A = lf_bf; lda = NEWS_DIM; koff = NEWS_DIM; klen = NEWS_DIM; }

    f32x4 acc[4];
#pragma unroll
    for (int b = 0; b < 4; b++) acc[b] = (f32x4){0.f, 0.f, 0.f, 0.f};

    const u16* Ap = A + (size_t)(r0 + m) * lda + q * 8;
    const u16* Wp = Wbf + (size_t)(c0 + m) * (2 * NEWS_DIM) + koff + q * 8;

    for (int k = 0; k < klen; k += 32) {
        short8 af, wf[4];
        af = *(const short8*)(Ap + k);
#pragma unroll
        for (int ct = 0; ct < 4; ct++) wf[ct] = *(const short8*)(Wp + ct * 16 * (2 * NEWS_DIM) + k);
#pragma unroll
        for (int ct = 0; ct < 4; ct++)
            acc[ct] = __builtin_amdgcn_mfma_f32_16x16x32_bf16(af, wf[ct], acc[ct], 0, 0, 0);
    }
    // C/D layout: col = lane&15, row = (lane>>4)*4 + i  [m89]
#pragma unroll
    for (int ct = 0; ct < 4; ct++)
#pragma unroll
        for (int i = 0; i < 4; i++) {
            int gr = r0 + q * 4 + i;
            int gc = c0 + ct * 16 + m;
            float v = acc[ct][i];
            if (is_pn) {
                pn[(size_t)gr * ATT_DIM + gc] = v + b1[gc];
            } else {
                int bb = gr / HL_, hh = gr - bb * HL_;
                plT[(size_t)(bb * ATT_DIM + gc) * HL_ + hh] = v;
            }
        }
}

// ---------------- K2: FUSED logits -> masked softmax -> out = attn x lf.
// R11: TWO WAVES PER (b,n). Occupancy was capped by total wave count
// (4096 waves / 1024 SIMDs = 4/SIMD resident; R10 measured VALUBusy 34%,
// latency-bound). Splitting a-dim (phase 1) and d-dim (phase 2) across a
// wave pair gives 8192 waves; __launch_bounds__(256,8) caps VGPR at 64 so
// all 8 blocks/CU (= 8 waves/SIMD) can be resident. Partial logits combine
// through 1KB LDS; softmax is recomputed per wave (shfl, ~30 VALU, cheap).
__global__ __launch_bounds__(256, 8) void attn_out_k(
    const float* __restrict__ pn, const float* __restrict__ plT,
    const float* __restrict__ w2, const int* __restrict__ lmask,
    const u16* __restrict__ lf_bf, float* __restrict__ out)
{
    __shared__ float part[4][64];              // partial logits, per wave
    __shared__ float at_s[4][64];              // per-wave attn (pair-redundant)
    int lane = threadIdx.x & 63;
    int wid = __builtin_amdgcn_readfirstlane((int)(threadIdx.x >> 6)); // 0..3
    int pair = wid >> 1;                       // which (b,n) of this block
    int half = wid & 1;                        // which half of a / d range
    int g = blockIdx.x * 2 + pair;             // (b,n) id in [0,4096)
    int b = g >> 6;
    int hl = (lane < HL_) ? lane : (HL_ - 1);  // clamp reads
    int aoff = half * 128;
    const float* pr = pn + (size_t)g * ATT_DIM + aoff;        // uniform -> s_load
    const float* pl = plT + ((size_t)b * ATT_DIM + aoff) * HL_ + hl;
    const float* w2o = w2 + aoff;

    float a0 = 0.f, a1 = 0.f, a2 = 0.f, a3 = 0.f;
#pragma unroll 2
    for (int a = 0; a < 128; a += 4) {
        float4 w4 = *(const float4*)(w2o + a);
        float4 p  = *(const float4*)(pr + a);  // wave-uniform
        float l0 = pl[(a + 0) * HL_];
        float l1 = pl[(a + 1) * HL_];
        float l2 = pl[(a + 2) * HL_];
        float l3 = pl[(a + 3) * HL_];
        a0 = __builtin_fmaf(fast_tanh(p.x + l0), w4.x, a0);
        a1 = __builtin_fmaf(fast_tanh(p.y + l1), w4.y, a1);
        a2 = __builtin_fmaf(fast_tanh(p.z + l2), w4.z, a2);
        a3 = __builtin_fmaf(fast_tanh(p.w + l3), w4.w, a3);
    }
    float acc = (a0 + a1) + (a2 + a3);
    part[wid][lane] = acc;
    __syncthreads();
    acc += part[wid ^ 1][lane];                // full 256-a logit

    int mv = (lane < HL_) ? lmask[b * HL_ + lane] : 0;
    float logit = mv ? acc : -1e9f;            // b2 dropped: softmax-invariant
    float mx = logit;
#pragma unroll
    for (int o = 32; o > 0; o >>= 1) mx = fmaxf(mx, __shfl_xor(mx, o));
    float e = EXP2F((logit - mx) * 1.44269504f);   // masked lanes -> 0
    float s = e;
#pragma unroll
    for (int o = 32; o > 0; o >>= 1) s += __shfl_xor(s, o);
    at_s[wid][lane] = e * RCPF(s);
    // no barrier: same wave writes & reads its own slice (lgkmcnt enforced)

    // phase 2: out[b,n][d]. Wave pair splits d: half 0 -> cols {0,1,2,3}*64,
    // half 1 -> cols {3,4,5,6}*64 (col 3 computed by both, stored by half 0
    // only -- overlap keeps the j-loop statically unrolled, no dyn indexing).
    const u16* lfb = lf_bf + (size_t)b * HL_ * NEWS_DIM + half * 192 + lane;
    float acc4[4];
#pragma unroll
    for (int j = 0; j < 4; j++) acc4[j] = 0.f;
    for (int h = 0; h < HL_; h++) {
        float av = at_s[wid][h];               // LDS broadcast
        const u16* row = lfb + (size_t)h * NEWS_DIM;
#pragma unroll
        for (int j = 0; j < 4; j++)
            acc4[j] = fmaf(av, bf2f(row[64 * j]), acc4[j]);
    }
    float* o0 = out + (size_t)g * NEWS_DIM + half * 192 + lane;
#pragma unroll
    for (int j = 0; j < 4; j++)
        if (half == 0 || j > 0)                // uniform predicate
            o0[64 * j] = acc4[j];
}

extern "C" void kernel_launch(void* const* d_in, const int* in_sizes, int n_in,
                              void* d_out, int out_size, void* d_ws, size_t ws_size,
                              hipStream_t stream) {
    const float* logv  = (const float*)d_in[0];  // (64,50,384) f32
    const int*   lmask = (const int*)d_in[1];    // (64,50) i32
    const float* newsv = (const float*)d_in[2];  // (64,64,384) f32
    const float* pos   = (const float*)d_in[3];  // (100,64) f32; row 0 == 0
    const float* W1    = (const float*)d_in[4];  // (256,896) f32
    const float* b1    = (const float*)d_in[5];  // (256,) f32
    const float* w2    = (const float*)d_in[6];  // (1,256) f32
    // b2 unused (softmax-invariant shift)

    float* out = (float*)d_out;                  // [user_log | nf], f32
    float* nf  = out + (size_t)B_ * NN_ * NEWS_DIM;

    // d_ws ~256 MiB. Byte offsets, 16B aligned:
    char* ws = (char*)d_ws;
    u16*   lf_bf = (u16*)(ws + 0);               // 3200x448 bf16  (2,867,200 B)
    u16*   Wbf   = (u16*)(ws + 2867200);         // 256x896 bf16   (458,752 B)
    u16*   nv_bf = (u16*)(ws + 3325952);         // 4096x384 bf16  (3,145,728 B)
    float* pn    = (float*)(ws + 6471680);       // 4096x256 f32   (4,194,304 B)
    float* plT   = (float*)(ws + 10665984);      // 64x256x50 f32  (3,276,800 B)

    prep_k    <<<C_TOT / 256, 256, 0, stream>>>(W1, newsv, logv, pos,
                                                Wbf, nv_bf, lf_bf, nf);
    gemm_k    <<<1824, 64, 0, stream>>>(nv_bf, lf_bf, Wbf, b1, pn, plT);
    attn_out_k<<<2048, 256, 0, stream>>>(pn, plT, w2, lmask, lf_bf, out);
}

// Round 2
// 133.073 us; speedup vs baseline: 2.0782x; 2.0782x over previous
//
#include <hip/hip_runtime.h>
#include <math.h>

typedef unsigned short u16;
typedef unsigned int   u32;

#define B_       64
#define NN_      64
#define HL_      50
#define IN_DIM   384
#define POS_DIM  64
#define ATT_DIM  256
#define NEWS_DIM 448   // IN_DIM + POS_DIM

typedef __attribute__((ext_vector_type(8))) short short8;   // bf16x8 MFMA frag
typedef __attribute__((ext_vector_type(4))) float f32x4;    // MFMA acc

#if __has_builtin(__builtin_amdgcn_exp2f)
#define EXP2F(x) __builtin_amdgcn_exp2f(x)
#else
#define EXP2F(x) exp2f(x)
#endif
#if __has_builtin(__builtin_amdgcn_rcpf)
#define RCPF(x) __builtin_amdgcn_rcpf(x)
#else
#define RCPF(x) (1.0f/(x))
#endif

__device__ __forceinline__ u16 f2bf(float f) {
    union { float f; u32 i; } v; v.f = f;
    u32 r = v.i + 0x7fffu + ((v.i >> 16) & 1u);   // RNE
    return (u16)(r >> 16);
}
__device__ __forceinline__ float bf2f(u16 u) {
    union { u32 i; float f; } v; v.i = ((u32)u) << 16; return v.f;
}
__device__ __forceinline__ uint2 pack4(float4 v) {
    return make_uint2((u32)f2bf(v.x) | ((u32)f2bf(v.y) << 16),
                      (u32)f2bf(v.z) | ((u32)f2bf(v.w) << 16));
}
// tanh(x) = 1 - 2/(1+2^(x*2*log2e)); v_exp+v_rcp saturate correctly at +-inf.
__device__ __forceinline__ float fast_tanh(float x) {
    float e = EXP2F(x * 2.88539008f);
    return 1.0f - 2.0f * RCPF(1.0f + e);
}

// prep segments, in 4-f32 chunks
#define C_W   57344u     // W1 (256x896) -> Wbf
#define C_NV  393216u    // newsv (4096x384) -> nv_bf AND nf f32 head
#define C_LG  307200u    // logv (3200x384) -> lf_bf head
#define C_PS  51200u     // pos rows 1..50 -> lf_bf tail
#define C_NZ  65536u     // nf f32 zero tail (4096x64)
#define C_TOT (C_W + C_NV + C_LG + C_PS + C_NZ)   // 874,496 = 3416*256

// ---------------- K0: bf16-convert W1/newsv/lf into ws; nf (f32) -> d_out.
__global__ __launch_bounds__(256) void prep_k(
    const float* __restrict__ W1, const float* __restrict__ newsv,
    const float* __restrict__ logv, const float* __restrict__ pos,
    u16* __restrict__ Wbf, u16* __restrict__ nv_bf, u16* __restrict__ lf_bf,
    float* __restrict__ nf)
{
    u32 i = blockIdx.x * 256u + threadIdx.x;
    if (i < C_W) {                                   // W1 -> Wbf
        float4 v = *(const float4*)(W1 + (size_t)i * 4u);
        *(uint2*)(Wbf + (size_t)i * 4u) = pack4(v);
        return;
    }
    i -= C_W;
    if (i < C_NV) {                                  // newsv -> nv_bf + nf head
        float4 v = *(const float4*)(newsv + (size_t)i * 4u);
        *(uint2*)(nv_bf + (size_t)i * 4u) = pack4(v);
        u32 e = i * 4u, r = e / IN_DIM, d = e - r * IN_DIM;
        *(float4*)(nf + (size_t)r * NEWS_DIM + d) = v;
        return;
    }
    i -= C_NV;
    if (i < C_LG) {                                  // logv -> lf_bf head
        float4 v = *(const float4*)(logv + (size_t)i * 4u);
        u32 e = i * 4u, r = e / IN_DIM, d = e - r * IN_DIM;
        *(uint2*)(lf_bf + (size_t)r * NEWS_DIM + d) = pack4(v);
        return;
    }
    i -= C_LG;
    if (i < C_PS) {                                  // pos rows 1..50 -> lf_bf tail
        u32 e = i * 4u, r = e / POS_DIM, d = e - r * POS_DIM;
        u32 h = r % HL_;
        float4 v = *(const float4*)(pos + (size_t)(1u + h) * POS_DIM + d);
        *(uint2*)(lf_bf + (size_t)r * NEWS_DIM + IN_DIM + d) = pack4(v);
        return;
    }
    i -= C_PS;
    if (i < C_NZ) {                                  // nf zero tail
        u32 e = i * 4u, r = e / POS_DIM, d = e - r * POS_DIM;
        *(float4*)(nf + (size_t)r * NEWS_DIM + IN_DIM + d) = make_float4(0.f, 0.f, 0.f, 0.f);
    }
}

// ---------------- K1: fused NT GEMMs, pure bf16 16B loads (R0-proven form;
// R11's 16x64 tiling is reverted -- could not isolate a win, and R0's 456
// blocks measured fine inside the 133us total).
// bid < 256: pn[4096x256] = nv_bf . Wbf[:, :384]^T + b1
// bid >= 256: plT[(b*256+a)*50+h] = lf_bf . Wbf[:, 448:]^T  (transposed store)
__global__ __launch_bounds__(64) void gemm_k(
    const u16* __restrict__ nv_bf, const u16* __restrict__ lf_bf,
    const u16* __restrict__ Wbf, const float* __restrict__ b1,
    float* __restrict__ pn, float* __restrict__ plT)
{
    int bid = blockIdx.x;
    int lane = threadIdx.x;
    int m = lane & 15, q = lane >> 4;
    bool is_pn = bid < 256;
    int r0, c0, lda, koff, klen;
    const u16* A;
    if (is_pn) { r0 = (bid & 63) * 64;       c0 = (bid >> 6) * 64; A = nv_bf; lda = IN_DIM;   koff = 0;        klen = IN_DIM; }
    else { int b2 = bid - 256; r0 = (b2 % 50) * 64; c0 = (b2 / 50) * 64; A = lf_bf; lda = NEWS_DIM; koff = NEWS_DIM; klen = NEWS_DIM; }

    f32x4 acc[4][4];
#pragma unroll
    for (int a = 0; a < 4; a++)
#pragma unroll
        for (int b = 0; b < 4; b++) acc[a][b] = (f32x4){0.f, 0.f, 0.f, 0.f};

    const u16* Ap = A + (size_t)(r0 + m) * lda + q * 8;
    const u16* Wp = Wbf + (size_t)(c0 + m) * (2 * NEWS_DIM) + koff + q * 8;

    for (int k = 0; k < klen; k += 32) {
        short8 af[4], wf[4];
#pragma unroll
        for (int rt = 0; rt < 4; rt++) af[rt] = *(const short8*)(Ap + rt * 16 * lda + k);
#pragma unroll
        for (int ct = 0; ct < 4; ct++) wf[ct] = *(const short8*)(Wp + ct * 16 * (2 * NEWS_DIM) + k);
#pragma unroll
        for (int rt = 0; rt < 4; rt++)
#pragma unroll
            for (int ct = 0; ct < 4; ct++)
                acc[rt][ct] = __builtin_amdgcn_mfma_f32_16x16x32_bf16(
                    af[rt], wf[ct], acc[rt][ct], 0, 0, 0);
    }
    // C/D layout: col = lane&15, row = (lane>>4)*4 + i  [m89]
#pragma unroll
    for (int rt = 0; rt < 4; rt++)
#pragma unroll
        for (int ct = 0; ct < 4; ct++)
#pragma unroll
            for (int i = 0; i < 4; i++) {
                int gr = r0 + rt * 16 + q * 4 + i;
                int gc = c0 + ct * 16 + m;
                float v = acc[rt][ct][i];
                if (is_pn) {
                    pn[(size_t)gr * ATT_DIM + gc] = v + b1[gc];
                } else {
                    int bb = gr / HL_, hh = gr - bb * HL_;
                    plT[(size_t)(bb * ATT_DIM + gc) * HL_ + hh] = v;
                }
            }
}

// ---------------- K2: FUSED logits -> masked softmax -> out = attn x lf.
// R0 structure (1 wave per (b,n), 1024 blocks x 4 waves -- proven 133us
// total). R12 changes, all locality/ILP, NOT occupancy (R11 post-mortem:
// raising occupancy to 78% thrashed L2 -> 185MB HBM fetch, 4x slower):
//  (1) XCD-clustered swizzle: XCD x (= blockIdx%8 round-robin) owns
//      b in [8x,8x+8). Per-XCD L2 working set ~1.3MB << 4MB -> plT/lf/pn
//      re-reads stay L2-resident. Wrong-mapping risk: pure permutation.
//  (2) g made wave-uniform via readfirstlane -> pn row + w2 load as s_load,
//      removing ~128 vector loads/wave from phase 1.
//  (3) phase 2 reads lf as packed u32 (2 bf16/load) -> 175 instead of 350
//      loads; float2 stores.
__global__ __launch_bounds__(256) void attn_out_k(
    const float* __restrict__ pn, const float* __restrict__ plT,
    const float* __restrict__ w2, const int* __restrict__ lmask,
    const u16* __restrict__ lf_bf, float* __restrict__ out)
{
    __shared__ float at_s[4][64];              // per-wave attn slices, 1 KB
    int lane = threadIdx.x & 63;
    int wid = __builtin_amdgcn_readfirstlane((int)(threadIdx.x >> 6));
    // XCD-clustered work mapping (bijective over 1024 blocks):
    int x     = blockIdx.x & 7;                // assumed XCD id
    int local = blockIdx.x >> 3;               // [0,128) within XCD
    int b     = x * 8 + (local >> 4);          // 8 b's per XCD
    int sub   = local & 15;                    // 16 blocks per b
    int g     = b * 64 + sub * 4 + wid;        // uniform (SGPR)
    int n_hl  = (lane < HL_) ? lane : (HL_ - 1);   // clamp reads
    const float* pr = pn + (size_t)g * ATT_DIM;    // uniform -> s_load
    const float* pl = plT + (size_t)b * ATT_DIM * HL_ + n_hl;

    float a0 = 0.f, a1 = 0.f, a2 = 0.f, a3 = 0.f;
#pragma unroll 4
    for (int a = 0; a < ATT_DIM; a += 4) {
        float4 w4 = *(const float4*)(w2 + a);  // uniform -> s_load
        float4 p  = *(const float4*)(pr + a);  // uniform -> s_load
        float l0 = pl[(a + 0) * HL_];
        float l1 = pl[(a + 1) * HL_];
        float l2 = pl[(a + 2) * HL_];
        float l3 = pl[(a + 3) * HL_];
        a0 = __builtin_fmaf(fast_tanh(p.x + l0), w4.x, a0);
        a1 = __builtin_fmaf(fast_tanh(p.y + l1), w4.y, a1);
        a2 = __builtin_fmaf(fast_tanh(p.z + l2), w4.z, a2);
        a3 = __builtin_fmaf(fast_tanh(p.w + l3), w4.w, a3);
    }
    float acc = (a0 + a1) + (a2 + a3);
    int mv = (lane < HL_) ? lmask[b * HL_ + lane] : 0;
    float logit = mv ? acc : -1e9f;            // b2 dropped: softmax-invariant
    float mx = logit;
#pragma unroll
    for (int o = 32; o > 0; o >>= 1) mx = fmaxf(mx, __shfl_xor(mx, o));
    float e = EXP2F((logit - mx) * 1.44269504f);   // masked lanes -> 0
    float s = e;
#pragma unroll
    for (int o = 32; o > 0; o >>= 1) s += __shfl_xor(s, o);
    at_s[wid][lane] = e * RCPF(s);
    // no barrier: same wave writes & reads its own slice (lgkmcnt enforced)

    // phase 2: out[b,n][d]. Packed u32 bf16 loads: lane covers d-pairs
    // {2*lane, 2*lane+1} + 128*j for j=0..2, plus tail d=384+2*lane (lane<32).
    // Lanes >=32 read a duplicate tail address (branch-free) and don't store.
    const u32* lfb32 = (const u32*)(lf_bf + (size_t)b * HL_ * NEWS_DIM);
    int tidx = 192 + (lane & 31);              // safe duplicate for lane>=32
    float p0 = 0.f, p1 = 0.f, p2 = 0.f, p3 = 0.f,
          p4 = 0.f, p5 = 0.f, p6 = 0.f, p7 = 0.f;
    for (int h = 0; h < HL_; h++) {
        float av = at_s[wid][h];               // LDS broadcast
        const u32* r32 = lfb32 + h * (NEWS_DIM / 2);
        u32 v0 = r32[lane];
        u32 v1 = r32[lane + 64];
        u32 v2 = r32[lane + 128];
        u32 v3 = r32[tidx];
        p0 = fmaf(av, bf2f((u16)v0),         p0);
        p1 = fmaf(av, bf2f((u16)(v0 >> 16)), p1);
        p2 = fmaf(av, bf2f((u16)v1),         p2);
        p3 = fmaf(av, bf2f((u16)(v1 >> 16)), p3);
        p4 = fmaf(av, bf2f((u16)v2),         p4);
        p5 = fmaf(av, bf2f((u16)(v2 >> 16)), p5);
        p6 = fmaf(av, bf2f((u16)v3),         p6);
        p7 = fmaf(av, bf2f((u16)(v3 >> 16)), p7);
    }
    float* orow = out + (size_t)g * NEWS_DIM;
    *(float2*)(orow +       2 * lane) = make_float2(p0, p1);
    *(float2*)(orow + 128 + 2 * lane) = make_float2(p2, p3);
    *(float2*)(orow + 256 + 2 * lane) = make_float2(p4, p5);
    if (lane < 32)
        *(float2*)(orow + 384 + 2 * lane) = make_float2(p6, p7);
}

extern "C" void kernel_launch(void* const* d_in, const int* in_sizes, int n_in,
                              void* d_out, int out_size, void* d_ws, size_t ws_size,
                              hipStream_t stream) {
    const float* logv  = (const float*)d_in[0];  // (64,50,384) f32
    const int*   lmask = (const int*)d_in[1];    // (64,50) i32
    const float* newsv = (const float*)d_in[2];  // (64,64,384) f32
    const float* pos   = (const float*)d_in[3];  // (100,64) f32; row 0 == 0
    const float* W1    = (const float*)d_in[4];  // (256,896) f32
    const float* b1    = (const float*)d_in[5];  // (256,) f32
    const float* w2    = (const float*)d_in[6];  // (1,256) f32
    // b2 unused (softmax-invariant shift)

    float* out = (float*)d_out;                  // [user_log | nf], f32
    float* nf  = out + (size_t)B_ * NN_ * NEWS_DIM;

    // d_ws ~256 MiB. Byte offsets, 16B aligned:
    char* ws = (char*)d_ws;
    u16*   lf_bf = (u16*)(ws + 0);               // 3200x448 bf16  (2,867,200 B)
    u16*   Wbf   = (u16*)(ws + 2867200);         // 256x896 bf16   (458,752 B)
    u16*   nv_bf = (u16*)(ws + 3325952);         // 4096x384 bf16  (3,145,728 B)
    float* pn    = (float*)(ws + 6471680);       // 4096x256 f32   (4,194,304 B)
    float* plT   = (float*)(ws + 10665984);      // 64x256x50 f32  (3,276,800 B)

    prep_k    <<<C_TOT / 256, 256, 0, stream>>>(W1, newsv, logv, pos,
                                                Wbf, nv_bf, lf_bf, nf);
    gemm_k    <<<456, 64, 0, stream>>>(nv_bf, lf_bf, Wbf, b1, pn, plT);
    attn_out_k<<<1024, 256, 0, stream>>>(pn, plT, w2, lmask, lf_bf, out);
}

// Round 3
// 128.677 us; speedup vs baseline: 2.1492x; 1.0342x over previous
//
#include <hip/hip_runtime.h>
#include <math.h>

typedef unsigned short u16;
typedef unsigned int   u32;

#define B_       64
#define NN_      64
#define HL_      50
#define IN_DIM   384
#define POS_DIM  64
#define ATT_DIM  256
#define NEWS_DIM 448   // IN_DIM + POS_DIM

typedef __attribute__((ext_vector_type(8))) short short8;   // bf16x8 MFMA frag
typedef __attribute__((ext_vector_type(4))) float f32x4;    // MFMA acc

#if __has_builtin(__builtin_amdgcn_exp2f)
#define EXP2F(x) __builtin_amdgcn_exp2f(x)
#else
#define EXP2F(x) exp2f(x)
#endif
#if __has_builtin(__builtin_amdgcn_rcpf)
#define RCPF(x) __builtin_amdgcn_rcpf(x)
#else
#define RCPF(x) (1.0f/(x))
#endif

__device__ __forceinline__ u16 f2bf(float f) {
    union { float f; u32 i; } v; v.f = f;
    u32 r = v.i + 0x7fffu + ((v.i >> 16) & 1u);   // RNE
    return (u16)(r >> 16);
}
__device__ __forceinline__ float bf2f(u16 u) {
    union { u32 i; float f; } v; v.i = ((u32)u) << 16; return v.f;
}
__device__ __forceinline__ uint2 pack4(float4 v) {
    return make_uint2((u32)f2bf(v.x) | ((u32)f2bf(v.y) << 16),
                      (u32)f2bf(v.z) | ((u32)f2bf(v.w) << 16));
}
// tanh(x) = 1 - 2/(1+2^(x*2*log2e)); v_exp+v_rcp saturate correctly at +-inf.
__device__ __forceinline__ float fast_tanh(float x) {
    float e = EXP2F(x * 2.88539008f);
    return 1.0f - 2.0f * RCPF(1.0f + e);
}

// prep segments, in 4-f32 chunks
#define C_W   57344u     // W1 (256x896) -> Wbf
#define C_NV  393216u    // newsv (4096x384) -> nv_bf AND nf f32 head
#define C_LG  307200u    // logv (3200x384) -> lf_bf head
#define C_PS  51200u     // pos rows 1..50 -> lf_bf tail
#define C_NZ  65536u     // nf f32 zero tail (4096x64)
#define C_TOT (C_W + C_NV + C_LG + C_PS + C_NZ)   // 874,496 = 3416*256

// ---------------- K0: bf16-convert W1/newsv/lf into ws; nf (f32) -> d_out.
__global__ __launch_bounds__(256) void prep_k(
    const float* __restrict__ W1, const float* __restrict__ newsv,
    const float* __restrict__ logv, const float* __restrict__ pos,
    u16* __restrict__ Wbf, u16* __restrict__ nv_bf, u16* __restrict__ lf_bf,
    float* __restrict__ nf)
{
    u32 i = blockIdx.x * 256u + threadIdx.x;
    if (i < C_W) {                                   // W1 -> Wbf
        float4 v = *(const float4*)(W1 + (size_t)i * 4u);
        *(uint2*)(Wbf + (size_t)i * 4u) = pack4(v);
        return;
    }
    i -= C_W;
    if (i < C_NV) {                                  // newsv -> nv_bf + nf head
        float4 v = *(const float4*)(newsv + (size_t)i * 4u);
        *(uint2*)(nv_bf + (size_t)i * 4u) = pack4(v);
        u32 e = i * 4u, r = e / IN_DIM, d = e - r * IN_DIM;
        *(float4*)(nf + (size_t)r * NEWS_DIM + d) = v;
        return;
    }
    i -= C_NV;
    if (i < C_LG) {                                  // logv -> lf_bf head
        float4 v = *(const float4*)(logv + (size_t)i * 4u);
        u32 e = i * 4u, r = e / IN_DIM, d = e - r * IN_DIM;
        *(uint2*)(lf_bf + (size_t)r * NEWS_DIM + d) = pack4(v);
        return;
    }
    i -= C_LG;
    if (i < C_PS) {                                  // pos rows 1..50 -> lf_bf tail
        u32 e = i * 4u, r = e / POS_DIM, d = e - r * POS_DIM;
        u32 h = r % HL_;
        float4 v = *(const float4*)(pos + (size_t)(1u + h) * POS_DIM + d);
        *(uint2*)(lf_bf + (size_t)r * NEWS_DIM + IN_DIM + d) = pack4(v);
        return;
    }
    i -= C_PS;
    if (i < C_NZ) {                                  // nf zero tail
        u32 e = i * 4u, r = e / POS_DIM, d = e - r * POS_DIM;
        *(float4*)(nf + (size_t)r * NEWS_DIM + IN_DIM + d) = make_float4(0.f, 0.f, 0.f, 0.f);
    }
}

// ---------------- K1: fused NT GEMMs, pure bf16 16B loads.
// R13: ISOLATED re-test of the 16x64-per-wave tiling (1824 waves vs R0's
// 456). R1 bundled this with the attn occupancy blowup so it was never
// measured alone. Rationale: 456 waves = 0.45/SIMD leaves every K-step's
// L2 load latency fully exposed; 1824 waves covers it with TLP. Extra W
// re-read traffic ~96MB, all L2 (~3us aggregate) -- cheap.
// bid < 1024: pn[4096x256] = nv_bf . Wbf[:, :384]^T + b1
// bid >= 1024: plT[(b*256+a)*50+h] = lf_bf . Wbf[:, 448:]^T (transposed store)
__global__ __launch_bounds__(64) void gemm_k(
    const u16* __restrict__ nv_bf, const u16* __restrict__ lf_bf,
    const u16* __restrict__ Wbf, const float* __restrict__ b1,
    float* __restrict__ pn, float* __restrict__ plT)
{
    int bid = blockIdx.x;
    int lane = threadIdx.x;
    int m = lane & 15, q = lane >> 4;
    bool is_pn = bid < 1024;
    int r0, c0, lda, koff, klen;
    const u16* A;
    if (is_pn) { r0 = (bid >> 2) * 16;  c0 = (bid & 3) * 64; A = nv_bf; lda = IN_DIM;   koff = 0;        klen = IN_DIM; }
    else { int b2 = bid - 1024; r0 = (b2 >> 2) * 16; c0 = (b2 & 3) * 64; A = lf_bf; lda = NEWS_DIM; koff = NEWS_DIM; klen = NEWS_DIM; }

    f32x4 acc[4];
#pragma unroll
    for (int b = 0; b < 4; b++) acc[b] = (f32x4){0.f, 0.f, 0.f, 0.f};

    const u16* Ap = A + (size_t)(r0 + m) * lda + q * 8;
    const u16* Wp = Wbf + (size_t)(c0 + m) * (2 * NEWS_DIM) + koff + q * 8;

    for (int k = 0; k < klen; k += 32) {
        short8 af, wf[4];
        af = *(const short8*)(Ap + k);
#pragma unroll
        for (int ct = 0; ct < 4; ct++) wf[ct] = *(const short8*)(Wp + ct * 16 * (2 * NEWS_DIM) + k);
#pragma unroll
        for (int ct = 0; ct < 4; ct++)
            acc[ct] = __builtin_amdgcn_mfma_f32_16x16x32_bf16(af, wf[ct], acc[ct], 0, 0, 0);
    }
    // C/D layout: col = lane&15, row = (lane>>4)*4 + i  [m89]
#pragma unroll
    for (int ct = 0; ct < 4; ct++)
#pragma unroll
        for (int i = 0; i < 4; i++) {
            int gr = r0 + q * 4 + i;
            int gc = c0 + ct * 16 + m;
            float v = acc[ct][i];
            if (is_pn) {
                pn[(size_t)gr * ATT_DIM + gc] = v + b1[gc];
            } else {
                int bb = gr / HL_, hh = gr - bb * HL_;
                plT[(size_t)(bb * ATT_DIM + gc) * HL_ + hh] = v;
            }
        }
}

// ---------------- K2: FUSED logits -> masked softmax -> out = attn x lf.
// BYTE-IDENTICAL to R2 (this round isolates the gemm change).
// R2 structure: 1 wave per (b,n), XCD-clustered swizzle, uniform g ->
// s_load for pn/w2, packed u32 bf16 phase-2 loads, float2 stores.
__global__ __launch_bounds__(256) void attn_out_k(
    const float* __restrict__ pn, const float* __restrict__ plT,
    const float* __restrict__ w2, const int* __restrict__ lmask,
    const u16* __restrict__ lf_bf, float* __restrict__ out)
{
    __shared__ float at_s[4][64];              // per-wave attn slices, 1 KB
    int lane = threadIdx.x & 63;
    int wid = __builtin_amdgcn_readfirstlane((int)(threadIdx.x >> 6));
    // XCD-clustered work mapping (bijective over 1024 blocks):
    int x     = blockIdx.x & 7;                // assumed XCD id
    int local = blockIdx.x >> 3;               // [0,128) within XCD
    int b     = x * 8 + (local >> 4);          // 8 b's per XCD
    int sub   = local & 15;                    // 16 blocks per b
    int g     = b * 64 + sub * 4 + wid;        // uniform (SGPR)
    int n_hl  = (lane < HL_) ? lane : (HL_ - 1);   // clamp reads
    const float* pr = pn + (size_t)g * ATT_DIM;    // uniform -> s_load
    const float* pl = plT + (size_t)b * ATT_DIM * HL_ + n_hl;

    float a0 = 0.f, a1 = 0.f, a2 = 0.f, a3 = 0.f;
#pragma unroll 4
    for (int a = 0; a < ATT_DIM; a += 4) {
        float4 w4 = *(const float4*)(w2 + a);  // uniform -> s_load
        float4 p  = *(const float4*)(pr + a);  // uniform -> s_load
        float l0 = pl[(a + 0) * HL_];
        float l1 = pl[(a + 1) * HL_];
        float l2 = pl[(a + 2) * HL_];
        float l3 = pl[(a + 3) * HL_];
        a0 = __builtin_fmaf(fast_tanh(p.x + l0), w4.x, a0);
        a1 = __builtin_fmaf(fast_tanh(p.y + l1), w4.y, a1);
        a2 = __builtin_fmaf(fast_tanh(p.z + l2), w4.z, a2);
        a3 = __builtin_fmaf(fast_tanh(p.w + l3), w4.w, a3);
    }
    float acc = (a0 + a1) + (a2 + a3);
    int mv = (lane < HL_) ? lmask[b * HL_ + lane] : 0;
    float logit = mv ? acc : -1e9f;            // b2 dropped: softmax-invariant
    float mx = logit;
#pragma unroll
    for (int o = 32; o > 0; o >>= 1) mx = fmaxf(mx, __shfl_xor(mx, o));
    float e = EXP2F((logit - mx) * 1.44269504f);   // masked lanes -> 0
    float s = e;
#pragma unroll
    for (int o = 32; o > 0; o >>= 1) s += __shfl_xor(s, o);
    at_s[wid][lane] = e * RCPF(s);
    // no barrier: same wave writes & reads its own slice (lgkmcnt enforced)

    // phase 2: out[b,n][d]. Packed u32 bf16 loads: lane covers d-pairs
    // {2*lane, 2*lane+1} + 128*j for j=0..2, plus tail d=384+2*lane (lane<32).
    // Lanes >=32 read a duplicate tail address (branch-free) and don't store.
    const u32* lfb32 = (const u32*)(lf_bf + (size_t)b * HL_ * NEWS_DIM);
    int tidx = 192 + (lane & 31);              // safe duplicate for lane>=32
    float p0 = 0.f, p1 = 0.f, p2 = 0.f, p3 = 0.f,
          p4 = 0.f, p5 = 0.f, p6 = 0.f, p7 = 0.f;
    for (int h = 0; h < HL_; h++) {
        float av = at_s[wid][h];               // LDS broadcast
        const u32* r32 = lfb32 + h * (NEWS_DIM / 2);
        u32 v0 = r32[lane];
        u32 v1 = r32[lane + 64];
        u32 v2 = r32[lane + 128];
        u32 v3 = r32[tidx];
        p0 = fmaf(av, bf2f((u16)v0),         p0);
        p1 = fmaf(av, bf2f((u16)(v0 >> 16)), p1);
        p2 = fmaf(av, bf2f((u16)v1),         p2);
        p3 = fmaf(av, bf2f((u16)(v1 >> 16)), p3);
        p4 = fmaf(av, bf2f((u16)v2),         p4);
        p5 = fmaf(av, bf2f((u16)(v2 >> 16)), p5);
        p6 = fmaf(av, bf2f((u16)v3),         p6);
        p7 = fmaf(av, bf2f((u16)(v3 >> 16)), p7);
    }
    float* orow = out + (size_t)g * NEWS_DIM;
    *(float2*)(orow +       2 * lane) = make_float2(p0, p1);
    *(float2*)(orow + 128 + 2 * lane) = make_float2(p2, p3);
    *(float2*)(orow + 256 + 2 * lane) = make_float2(p4, p5);
    if (lane < 32)
        *(float2*)(orow + 384 + 2 * lane) = make_float2(p6, p7);
}

extern "C" void kernel_launch(void* const* d_in, const int* in_sizes, int n_in,
                              void* d_out, int out_size, void* d_ws, size_t ws_size,
                              hipStream_t stream) {
    const float* logv  = (const float*)d_in[0];  // (64,50,384) f32
    const int*   lmask = (const int*)d_in[1];    // (64,50) i32
    const float* newsv = (const float*)d_in[2];  // (64,64,384) f32
    const float* pos   = (const float*)d_in[3];  // (100,64) f32; row 0 == 0
    const float* W1    = (const float*)d_in[4];  // (256,896) f32
    const float* b1    = (const float*)d_in[5];  // (256,) f32
    const float* w2    = (const float*)d_in[6];  // (1,256) f32
    // b2 unused (softmax-invariant shift)

    float* out = (float*)d_out;                  // [user_log | nf], f32
    float* nf  = out + (size_t)B_ * NN_ * NEWS_DIM;

    // d_ws ~256 MiB. Byte offsets, 16B aligned:
    char* ws = (char*)d_ws;
    u16*   lf_bf = (u16*)(ws + 0);               // 3200x448 bf16  (2,867,200 B)
    u16*   Wbf   = (u16*)(ws + 2867200);         // 256x896 bf16   (458,752 B)
    u16*   nv_bf = (u16*)(ws + 3325952);         // 4096x384 bf16  (3,145,728 B)
    float* pn    = (float*)(ws + 6471680);       // 4096x256 f32   (4,194,304 B)
    float* plT   = (float*)(ws + 10665984);      // 64x256x50 f32  (3,276,800 B)

    prep_k    <<<C_TOT / 256, 256, 0, stream>>>(W1, newsv, logv, pos,
                                                Wbf, nv_bf, lf_bf, nf);
    gemm_k    <<<1824, 64, 0, stream>>>(nv_bf, lf_bf, Wbf, b1, pn, plT);
    attn_out_k<<<1024, 256, 0, stream>>>(pn, plT, w2, lmask, lf_bf, out);
}

// Round 4
// 127.703 us; speedup vs baseline: 2.1656x; 1.0076x over previous
//
#include <hip/hip_runtime.h>
#include <math.h>

typedef unsigned short u16;
typedef unsigned int   u32;

#define B_       64
#define NN_      64
#define HL_      50
#define IN_DIM   384
#define POS_DIM  64
#define ATT_DIM  256
#define NEWS_DIM 448   // IN_DIM + POS_DIM

typedef __attribute__((ext_vector_type(8))) short short8;   // bf16x8 MFMA frag
typedef __attribute__((ext_vector_type(4))) float f32x4;    // MFMA acc

#if __has_builtin(__builtin_amdgcn_exp2f)
#define EXP2F(x) __builtin_amdgcn_exp2f(x)
#else
#define EXP2F(x) exp2f(x)
#endif
#if __has_builtin(__builtin_amdgcn_rcpf)
#define RCPF(x) __builtin_amdgcn_rcpf(x)
#else
#define RCPF(x) (1.0f/(x))
#endif

__device__ __forceinline__ u16 f2bf(float f) {
    union { float f; u32 i; } v; v.f = f;
    u32 r = v.i + 0x7fffu + ((v.i >> 16) & 1u);   // RNE
    return (u16)(r >> 16);
}
__device__ __forceinline__ float bf2f(u16 u) {
    union { u32 i; float f; } v; v.i = ((u32)u) << 16; return v.f;
}
__device__ __forceinline__ uint2 pack4(float4 v) {
    return make_uint2((u32)f2bf(v.x) | ((u32)f2bf(v.y) << 16),
                      (u32)f2bf(v.z) | ((u32)f2bf(v.w) << 16));
}
// tanh(x) = 1 - 2/(1+2^(x*2*log2e)); v_exp+v_rcp saturate correctly at +-inf.
__device__ __forceinline__ float fast_tanh(float x) {
    float e = EXP2F(x * 2.88539008f);
    return 1.0f - 2.0f * RCPF(1.0f + e);
}

// ---------------- K0: bf16-convert W1/newsv/lf into ws; nf (f32) -> d_out.
// R14: XCD-ALIGNED segments. All data belonging to batch b is WRITTEN by
// blocks on XCD b>>3 (assuming round-robin XCD = blockIdx%8), matching
// gemm's readers (below) and attn's readers. Cross-XCD L2s aren't
// snooped, so producer/consumer XCD alignment is what makes the L2
// locality real (R2's reader-only swizzle was a measured null).
// Layout: bid<2936: 8 XCD groups x 367 blocks {192 NV | 150 LG | 25 PS};
// then 224 W blocks, then 256 NZ blocks (no aligned consumer).
__global__ __launch_bounds__(256) void prep_k(
    const float* __restrict__ W1, const float* __restrict__ newsv,
    const float* __restrict__ logv, const float* __restrict__ pos,
    u16* __restrict__ Wbf, u16* __restrict__ nv_bf, u16* __restrict__ lf_bf,
    float* __restrict__ nf)
{
    u32 bid = blockIdx.x, tid = threadIdx.x;
    if (bid < 2936u) {
        u32 x = bid & 7u, j = bid >> 3;
        if (j < 192u) {            // newsv rows [512x, 512x+512) -> nv_bf + nf
            u32 idx = j * 256u + tid;              // < 49152
            u32 r = 512u * x + idx / 96u, d4 = idx % 96u;
            float4 v = *(const float4*)(newsv + (size_t)r * IN_DIM + d4 * 4u);
            *(uint2*)(nv_bf + (size_t)r * IN_DIM + d4 * 4u) = pack4(v);
            *(float4*)(nf + (size_t)r * NEWS_DIM + d4 * 4u) = v;
        } else if (j < 342u) {     // logv rows [400x, 400x+400) -> lf_bf head
            u32 idx = (j - 192u) * 256u + tid;     // < 38400
            u32 r = 400u * x + idx / 96u, d4 = idx % 96u;
            float4 v = *(const float4*)(logv + (size_t)r * IN_DIM + d4 * 4u);
            *(uint2*)(lf_bf + (size_t)r * NEWS_DIM + d4 * 4u) = pack4(v);
        } else {                   // pos tail, lf rows [400x, 400x+400)
            u32 idx = (j - 342u) * 256u + tid;     // < 6400
            u32 r = 400u * x + idx / 16u, d4 = idx % 16u;
            u32 h = r % HL_;
            float4 v = *(const float4*)(pos + (size_t)(1u + h) * POS_DIM + d4 * 4u);
            *(uint2*)(lf_bf + (size_t)r * NEWS_DIM + IN_DIM + d4 * 4u) = pack4(v);
        }
        return;
    }
    bid -= 2936u;
    if (bid < 224u) {              // W1 -> Wbf (read-shared; placement moot)
        u32 i = bid * 256u + tid;
        float4 v = *(const float4*)(W1 + (size_t)i * 4u);
        *(uint2*)(Wbf + (size_t)i * 4u) = pack4(v);
        return;
    }
    bid -= 224u;
    {                              // nf zero tail (no downstream reader)
        u32 i = bid * 256u + tid;  // < 65536
        u32 r = i / 16u, d4 = i % 16u;
        *(float4*)(nf + (size_t)r * NEWS_DIM + IN_DIM + d4 * 4u) =
            make_float4(0.f, 0.f, 0.f, 0.f);
    }
}

// ---------------- K1: fused NT GEMMs, 16x64-per-wave tiles (R3-proven,
// -4.4us isolated). R14: XCD-aligned tile map. 1824 = 8 XCDs x 228 tiles
// {128 pn + 100 pl}. XCD x computes pn rows of b in [8x,8x+8) and pl rows
// [400x,400x+400) -- the exact panels attn's XCD-x blocks read, and the
// nv/lf rows prep wrote on XCD x. Inner body unchanged.
// pn[4096x256] = nv_bf . Wbf[:, :384]^T + b1
// plT[(b*256+a)*50+h] = lf_bf . Wbf[:, 448:]^T (transposed store)
__global__ __launch_bounds__(64) void gemm_k(
    const u16* __restrict__ nv_bf, const u16* __restrict__ lf_bf,
    const u16* __restrict__ Wbf, const float* __restrict__ b1,
    float* __restrict__ pn, float* __restrict__ plT)
{
    int bid = blockIdx.x;          // 1824 = 8*228
    int lane = threadIdx.x;
    int m = lane & 15, q = lane >> 4;
    int x = bid & 7, j = bid >> 3; // j in [0,228)
    bool is_pn = j < 128;
    int r0, c0, lda, koff, klen;
    const u16* A;
    if (is_pn) {                   // 16 tiles per b: 4 row-bands x 4 col-tiles
        int b = x * 8 + (j >> 4);
        r0 = b * 64 + ((j >> 2) & 3) * 16;
        c0 = (j & 3) * 64;
        A = nv_bf; lda = IN_DIM;   koff = 0;        klen = IN_DIM;
    } else {                       // 100 tiles: 25 row-bands x 4 col-tiles
        int j2 = j - 128;
        r0 = 400 * x + (j2 >> 2) * 16;
        c0 = (j2 & 3) * 64;
        A = lf_bf; lda = NEWS_DIM; koff = NEWS_DIM; klen = NEWS_DIM;
    }

    f32x4 acc[4];
#pragma unroll
    for (int b = 0; b < 4; b++) acc[b] = (f32x4){0.f, 0.f, 0.f, 0.f};

    const u16* Ap = A + (size_t)(r0 + m) * lda + q * 8;
    const u16* Wp = Wbf + (size_t)(c0 + m) * (2 * NEWS_DIM) + koff + q * 8;

    for (int k = 0; k < klen; k += 32) {
        short8 af, wf[4];
        af = *(const short8*)(Ap + k);
#pragma unroll
        for (int ct = 0; ct < 4; ct++) wf[ct] = *(const short8*)(Wp + ct * 16 * (2 * NEWS_DIM) + k);
#pragma unroll
        for (int ct = 0; ct < 4; ct++)
            acc[ct] = __builtin_amdgcn_mfma_f32_16x16x32_bf16(af, wf[ct], acc[ct], 0, 0, 0);
    }
    // C/D layout: col = lane&15, row = (lane>>4)*4 + i  [m89]
#pragma unroll
    for (int ct = 0; ct < 4; ct++)
#pragma unroll
        for (int i = 0; i < 4; i++) {
            int gr = r0 + q * 4 + i;
            int gc = c0 + ct * 16 + m;
            float v = acc[ct][i];
            if (is_pn) {
                pn[(size_t)gr * ATT_DIM + gc] = v + b1[gc];
            } else {
                int bb = gr / HL_, hh = gr - bb * HL_;
                plT[(size_t)(bb * ATT_DIM + gc) * HL_ + hh] = v;
            }
        }
}

// ---------------- K2: FUSED logits -> masked softmax -> out = attn x lf.
// BYTE-IDENTICAL to R2/R3. XCD x handles b in [8x,8x+8) -- now matching
// the writers of pn/plT/lf_bf above.
__global__ __launch_bounds__(256) void attn_out_k(
    const float* __restrict__ pn, const float* __restrict__ plT,
    const float* __restrict__ w2, const int* __restrict__ lmask,
    const u16* __restrict__ lf_bf, float* __restrict__ out)
{
    __shared__ float at_s[4][64];              // per-wave attn slices, 1 KB
    int lane = threadIdx.x & 63;
    int wid = __builtin_amdgcn_readfirstlane((int)(threadIdx.x >> 6));
    // XCD-clustered work mapping (bijective over 1024 blocks):
    int x     = blockIdx.x & 7;                // assumed XCD id
    int local = blockIdx.x >> 3;               // [0,128) within XCD
    int b     = x * 8 + (local >> 4);          // 8 b's per XCD
    int sub   = local & 15;                    // 16 blocks per b
    int g     = b * 64 + sub * 4 + wid;        // uniform (SGPR)
    int n_hl  = (lane < HL_) ? lane : (HL_ - 1);   // clamp reads
    const float* pr = pn + (size_t)g * ATT_DIM;    // uniform -> s_load
    const float* pl = plT + (size_t)b * ATT_DIM * HL_ + n_hl;

    float a0 = 0.f, a1 = 0.f, a2 = 0.f, a3 = 0.f;
#pragma unroll 4
    for (int a = 0; a < ATT_DIM; a += 4) {
        float4 w4 = *(const float4*)(w2 + a);  // uniform -> s_load
        float4 p  = *(const float4*)(pr + a);  // uniform -> s_load
        float l0 = pl[(a + 0) * HL_];
        float l1 = pl[(a + 1) * HL_];
        float l2 = pl[(a + 2) * HL_];
        float l3 = pl[(a + 3) * HL_];
        a0 = __builtin_fmaf(fast_tanh(p.x + l0), w4.x, a0);
        a1 = __builtin_fmaf(fast_tanh(p.y + l1), w4.y, a1);
        a2 = __builtin_fmaf(fast_tanh(p.z + l2), w4.z, a2);
        a3 = __builtin_fmaf(fast_tanh(p.w + l3), w4.w, a3);
    }
    float acc = (a0 + a1) + (a2 + a3);
    int mv = (lane < HL_) ? lmask[b * HL_ + lane] : 0;
    float logit = mv ? acc : -1e9f;            // b2 dropped: softmax-invariant
    float mx = logit;
#pragma unroll
    for (int o = 32; o > 0; o >>= 1) mx = fmaxf(mx, __shfl_xor(mx, o));
    float e = EXP2F((logit - mx) * 1.44269504f);   // masked lanes -> 0
    float s = e;
#pragma unroll
    for (int o = 32; o > 0; o >>= 1) s += __shfl_xor(s, o);
    at_s[wid][lane] = e * RCPF(s);
    // no barrier: same wave writes & reads its own slice (lgkmcnt enforced)

    // phase 2: out[b,n][d]. Packed u32 bf16 loads: lane covers d-pairs
    // {2*lane, 2*lane+1} + 128*j for j=0..2, plus tail d=384+2*lane (lane<32).
    // Lanes >=32 read a duplicate tail address (branch-free) and don't store.
    const u32* lfb32 = (const u32*)(lf_bf + (size_t)b * HL_ * NEWS_DIM);
    int tidx = 192 + (lane & 31);              // safe duplicate for lane>=32
    float p0 = 0.f, p1 = 0.f, p2 = 0.f, p3 = 0.f,
          p4 = 0.f, p5 = 0.f, p6 = 0.f, p7 = 0.f;
    for (int h = 0; h < HL_; h++) {
        float av = at_s[wid][h];               // LDS broadcast
        const u32* r32 = lfb32 + h * (NEWS_DIM / 2);
        u32 v0 = r32[lane];
        u32 v1 = r32[lane + 64];
        u32 v2 = r32[lane + 128];
        u32 v3 = r32[tidx];
        p0 = fmaf(av, bf2f((u16)v0),         p0);
        p1 = fmaf(av, bf2f((u16)(v0 >> 16)), p1);
        p2 = fmaf(av, bf2f((u16)v1),         p2);
        p3 = fmaf(av, bf2f((u16)(v1 >> 16)), p3);
        p4 = fmaf(av, bf2f((u16)v2),         p4);
        p5 = fmaf(av, bf2f((u16)(v2 >> 16)), p5);
        p6 = fmaf(av, bf2f((u16)v3),         p6);
        p7 = fmaf(av, bf2f((u16)(v3 >> 16)), p7);
    }
    float* orow = out + (size_t)g * NEWS_DIM;
    *(float2*)(orow +       2 * lane) = make_float2(p0, p1);
    *(float2*)(orow + 128 + 2 * lane) = make_float2(p2, p3);
    *(float2*)(orow + 256 + 2 * lane) = make_float2(p4, p5);
    if (lane < 32)
        *(float2*)(orow + 384 + 2 * lane) = make_float2(p6, p7);
}

extern "C" void kernel_launch(void* const* d_in, const int* in_sizes, int n_in,
                              void* d_out, int out_size, void* d_ws, size_t ws_size,
                              hipStream_t stream) {
    const float* logv  = (const float*)d_in[0];  // (64,50,384) f32
    const int*   lmask = (const int*)d_in[1];    // (64,50) i32
    const float* newsv = (const float*)d_in[2];  // (64,64,384) f32
    const float* pos   = (const float*)d_in[3];  // (100,64) f32; row 0 == 0
    const float* W1    = (const float*)d_in[4];  // (256,896) f32
    const float* b1    = (const float*)d_in[5];  // (256,) f32
    const float* w2    = (const float*)d_in[6];  // (1,256) f32
    // b2 unused (softmax-invariant shift)

    float* out = (float*)d_out;                  // [user_log | nf], f32
    float* nf  = out + (size_t)B_ * NN_ * NEWS_DIM;

    // d_ws ~256 MiB. Byte offsets, 16B aligned:
    char* ws = (char*)d_ws;
    u16*   lf_bf = (u16*)(ws + 0);               // 3200x448 bf16  (2,867,200 B)
    u16*   Wbf   = (u16*)(ws + 2867200);         // 256x896 bf16   (458,752 B)
    u16*   nv_bf = (u16*)(ws + 3325952);         // 4096x384 bf16  (3,145,728 B)
    float* pn    = (float*)(ws + 6471680);       // 4096x256 f32   (4,194,304 B)
    float* plT   = (float*)(ws + 10665984);      // 64x256x50 f32  (3,276,800 B)

    prep_k    <<<3416, 256, 0, stream>>>(W1, newsv, logv, pos,
                                         Wbf, nv_bf, lf_bf, nf);
    gemm_k    <<<1824, 64, 0, stream>>>(nv_bf, lf_bf, Wbf, b1, pn, plT);
    attn_out_k<<<1024, 256, 0, stream>>>(pn, plT, w2, lmask, lf_bf, out);
}